// Round 1
// baseline (307.854 us; speedup 1.0000x reference)
//
#include <hip/hip_runtime.h>

#define B 8
#define TQ 64
#define TK 8192
#define H 256

#define KT 128      // k-tile per scores block
#define HC 64       // h chunk staged in LDS
#define QPAD 68     // 64 + 4 (keep float4 alignment, break bank stride)
#define KPAD 132    // 128 + 4
#define KC 256      // k per context block

// ---------------- Kernel 1: qt = query @ Wa_w ; qb = query . Wa_b ----------
__global__ __launch_bounds__(256) void qtransform_kernel(
    const float* __restrict__ query, const float* __restrict__ Wa_w,
    const float* __restrict__ Wa_b, float* __restrict__ qt, float* __restrict__ qb)
{
    __shared__ float q_s[H];
    __shared__ float red[4];
    const int r = blockIdx.x;          // row in [0, B*TQ)
    const int t = threadIdx.x;         // 0..255
    q_s[t] = query[r * H + t];
    __syncthreads();

    float a0 = 0.f, a1 = 0.f, a2 = 0.f, a3 = 0.f;
    for (int o = 0; o < H; o += 4) {
        a0 += q_s[o + 0] * Wa_w[(o + 0) * H + t];
        a1 += q_s[o + 1] * Wa_w[(o + 1) * H + t];
        a2 += q_s[o + 2] * Wa_w[(o + 2) * H + t];
        a3 += q_s[o + 3] * Wa_w[(o + 3) * H + t];
    }
    qt[r * H + t] = (a0 + a1) + (a2 + a3);

    float p = q_s[t] * Wa_b[t];
    for (int off = 32; off > 0; off >>= 1) p += __shfl_down(p, off, 64);
    if ((t & 63) == 0) red[t >> 6] = p;
    __syncthreads();
    if (t == 0) qb[r] = (red[0] + red[1]) + (red[2] + red[3]);
}

// ---------------- Kernel 2: raw scores = qt . keys^T + qb ------------------
// grid (TK/KT, B); block 256. Output tile 64q x 128k, 4q x 8k per thread.
__global__ __launch_bounds__(256) void scores_kernel(
    const float* __restrict__ qt, const float* __restrict__ qb,
    const float* __restrict__ keys, float* __restrict__ wout)
{
    __shared__ float qt_s[HC][QPAD];
    __shared__ float k_s[HC][KPAD];
    const int t   = threadIdx.x;
    const int kt  = blockIdx.x;      // 0..63
    const int b   = blockIdx.y;      // 0..7
    const int k0g = kt * KT;

    const int tq = t >> 4;           // 0..15
    const int tk = t & 15;           // 0..15
    const int q0 = tq * 4, kk0 = tk * 8;

    float acc[4][8];
    #pragma unroll
    for (int i = 0; i < 4; ++i)
        #pragma unroll
        for (int j = 0; j < 8; ++j) acc[i][j] = 0.f;

    for (int hc = 0; hc < H; hc += HC) {
        __syncthreads();
        // stage qt chunk: 64q x 64h -> qt_s[h][q]
        #pragma unroll
        for (int i = 0; i < 4; ++i) {
            int idx = t + 256 * i;          // float4 index, 0..1023
            int q = idx >> 4, hq = idx & 15;
            float4 v = *(const float4*)&qt[(b * TQ + q) * H + hc + hq * 4];
            qt_s[hq * 4 + 0][q] = v.x; qt_s[hq * 4 + 1][q] = v.y;
            qt_s[hq * 4 + 2][q] = v.z; qt_s[hq * 4 + 3][q] = v.w;
        }
        // stage keys chunk: 128k x 64h -> k_s[h][k]
        #pragma unroll
        for (int i = 0; i < 8; ++i) {
            int idx = t + 256 * i;          // 0..2047
            int k = idx >> 4, hq = idx & 15;
            float4 v = *(const float4*)&keys[(size_t)(b * TK + k0g + k) * H + hc + hq * 4];
            k_s[hq * 4 + 0][k] = v.x; k_s[hq * 4 + 1][k] = v.y;
            k_s[hq * 4 + 2][k] = v.z; k_s[hq * 4 + 3][k] = v.w;
        }
        __syncthreads();
        #pragma unroll 8
        for (int h = 0; h < HC; ++h) {
            float4 qa  = *(const float4*)&qt_s[h][q0];
            float4 kb0 = *(const float4*)&k_s[h][kk0];
            float4 kb1 = *(const float4*)&k_s[h][kk0 + 4];
            const float qv[4] = {qa.x, qa.y, qa.z, qa.w};
            const float kv[8] = {kb0.x, kb0.y, kb0.z, kb0.w, kb1.x, kb1.y, kb1.z, kb1.w};
            #pragma unroll
            for (int i = 0; i < 4; ++i)
                #pragma unroll
                for (int j = 0; j < 8; ++j)
                    acc[i][j] += qv[i] * kv[j];
        }
    }
    #pragma unroll
    for (int i = 0; i < 4; ++i) {
        float bias = qb[b * TQ + q0 + i];
        float4 o0 = make_float4(acc[i][0] + bias, acc[i][1] + bias,
                                acc[i][2] + bias, acc[i][3] + bias);
        float4 o1 = make_float4(acc[i][4] + bias, acc[i][5] + bias,
                                acc[i][6] + bias, acc[i][7] + bias);
        float* dst = &wout[(size_t)(b * TQ + q0 + i) * TK + k0g + kk0];
        *(float4*)dst = o0;
        *(float4*)(dst + 4) = o1;
    }
}

// ---------------- Kernel 3: row softmax in place ---------------------------
__global__ __launch_bounds__(256) void softmax_kernel(float* __restrict__ w)
{
    const int r = blockIdx.x;     // 0..511
    const int t = threadIdx.x;
    float* row = w + (size_t)r * TK;
    __shared__ float redm[4];
    __shared__ float reds[4];

    float e[32];
    float m = -1e30f;
    #pragma unroll
    for (int i = 0; i < 32; ++i) { e[i] = row[t + i * 256]; m = fmaxf(m, e[i]); }
    for (int off = 32; off > 0; off >>= 1) m = fmaxf(m, __shfl_xor(m, off, 64));
    if ((t & 63) == 0) redm[t >> 6] = m;
    __syncthreads();
    m = fmaxf(fmaxf(redm[0], redm[1]), fmaxf(redm[2], redm[3]));

    float s = 0.f;
    #pragma unroll
    for (int i = 0; i < 32; ++i) { e[i] = __expf(e[i] - m); s += e[i]; }
    for (int off = 32; off > 0; off >>= 1) s += __shfl_xor(s, off, 64);
    if ((t & 63) == 0) reds[t >> 6] = s;
    __syncthreads();
    s = (reds[0] + reds[1]) + (reds[2] + reds[3]);
    const float inv = 1.0f / s;
    #pragma unroll
    for (int i = 0; i < 32; ++i) row[t + i * 256] = e[i] * inv;
}

// ---------------- Kernel 4: context = weights @ keys -----------------------
// grid (TK/KC, B); block 256. Each block: 64q x 256h partial over KC keys.
__global__ __launch_bounds__(256) void context_kernel(
    const float* __restrict__ w, const float* __restrict__ keys,
    float* __restrict__ ctx)
{
    __shared__ float w_s[TQ][128];
    const int t  = threadIdx.x;
    const int kc = blockIdx.x;   // 0..31
    const int b  = blockIdx.y;
    const int hg = t & 63;       // float4 index over h
    const int qg = t >> 6;       // 0..3

    float acc[16][4];
    #pragma unroll
    for (int j = 0; j < 16; ++j)
        #pragma unroll
        for (int c = 0; c < 4; ++c) acc[j][c] = 0.f;

    for (int sub = 0; sub < 2; ++sub) {
        const int k0 = kc * KC + sub * 128;
        __syncthreads();
        #pragma unroll
        for (int i = 0; i < 8; ++i) {
            int idx = t + 256 * i;            // float4 idx in 64x128 tile
            int q = idx >> 5, k4 = idx & 31;
            *(float4*)&w_s[q][k4 * 4] =
                *(const float4*)&w[(size_t)(b * TQ + q) * TK + k0 + k4 * 4];
        }
        __syncthreads();
        for (int k = 0; k < 128; k += 4) {
            float4 kv[4];
            #pragma unroll
            for (int u = 0; u < 4; ++u)
                kv[u] = *(const float4*)&keys[(size_t)(b * TK + k0 + k + u) * H + hg * 4];
            #pragma unroll
            for (int j = 0; j < 16; ++j) {
                float4 wv = *(const float4*)&w_s[qg * 16 + j][k];
                acc[j][0] += wv.x * kv[0].x + wv.y * kv[1].x + wv.z * kv[2].x + wv.w * kv[3].x;
                acc[j][1] += wv.x * kv[0].y + wv.y * kv[1].y + wv.z * kv[2].y + wv.w * kv[3].y;
                acc[j][2] += wv.x * kv[0].z + wv.y * kv[1].z + wv.z * kv[2].z + wv.w * kv[3].z;
                acc[j][3] += wv.x * kv[0].w + wv.y * kv[1].w + wv.z * kv[2].w + wv.w * kv[3].w;
            }
        }
    }
    #pragma unroll
    for (int j = 0; j < 16; ++j) {
        float* dst = &ctx[(size_t)(b * TQ + qg * 16 + j) * H + hg * 4];
        atomicAdd(dst + 0, acc[j][0]);
        atomicAdd(dst + 1, acc[j][1]);
        atomicAdd(dst + 2, acc[j][2]);
        atomicAdd(dst + 3, acc[j][3]);
    }
}

extern "C" void kernel_launch(void* const* d_in, const int* in_sizes, int n_in,
                              void* d_out, int out_size, void* d_ws, size_t ws_size,
                              hipStream_t stream) {
    const float* query = (const float*)d_in[0];
    const float* keys  = (const float*)d_in[1];
    const float* Wa_w  = (const float*)d_in[2];
    const float* Wa_b  = (const float*)d_in[3];

    float* ctx = (float*)d_out;                 // [B,TQ,H]
    float* wts = (float*)d_out + B * TQ * H;    // [B,TQ,TK]
    float* qt  = (float*)d_ws;                  // [B*TQ, H]
    float* qb  = qt + B * TQ * H;               // [B*TQ]

    hipMemsetAsync(ctx, 0, (size_t)B * TQ * H * sizeof(float), stream);
    qtransform_kernel<<<B * TQ, 256, 0, stream>>>(query, Wa_w, Wa_b, qt, qb);
    scores_kernel<<<dim3(TK / KT, B), 256, 0, stream>>>(qt, qb, keys, wts);
    softmax_kernel<<<B * TQ, 256, 0, stream>>>(wts);
    context_kernel<<<dim3(TK / KC, B), 256, 0, stream>>>(wts, keys, ctx);
}

// Round 2
// 190.565 us; speedup vs baseline: 1.6155x; 1.6155x over previous
//
#include <hip/hip_runtime.h>

#define B 8
#define TQ 64
#define TK 8192
#define H 256

#define KT 128      // k-tile per scores block
#define HC 64       // h chunk staged in LDS
#define QPAD 68     // 64 + 4
#define KPAD 132    // 128 + 4
#define KC 256      // k per context block (fallback atomic path)

// context split-k params
#define KSPLIT 32
#define KPB (TK / KSPLIT)   // 256 k per block
#define CH 64               // h per block
#define CKC 64              // k chunk staged in LDS
#define CPAD 68

// ---------------- Kernel 1: qt = query @ Wa_w ; qb = query . Wa_b ----------
__global__ __launch_bounds__(256) void qtransform_kernel(
    const float* __restrict__ query, const float* __restrict__ Wa_w,
    const float* __restrict__ Wa_b, float* __restrict__ qt, float* __restrict__ qb)
{
    __shared__ float q_s[H];
    __shared__ float red[4];
    const int r = blockIdx.x;          // row in [0, B*TQ)
    const int t = threadIdx.x;         // 0..255
    q_s[t] = query[r * H + t];
    __syncthreads();

    float a0 = 0.f, a1 = 0.f, a2 = 0.f, a3 = 0.f;
    for (int o = 0; o < H; o += 4) {
        a0 += q_s[o + 0] * Wa_w[(o + 0) * H + t];
        a1 += q_s[o + 1] * Wa_w[(o + 1) * H + t];
        a2 += q_s[o + 2] * Wa_w[(o + 2) * H + t];
        a3 += q_s[o + 3] * Wa_w[(o + 3) * H + t];
    }
    qt[r * H + t] = (a0 + a1) + (a2 + a3);

    float p = q_s[t] * Wa_b[t];
    for (int off = 32; off > 0; off >>= 1) p += __shfl_down(p, off, 64);
    if ((t & 63) == 0) red[t >> 6] = p;
    __syncthreads();
    if (t == 0) qb[r] = (red[0] + red[1]) + (red[2] + red[3]);
}

// ---------------- Kernel 2: raw scores = qt . keys^T + qb ------------------
__global__ __launch_bounds__(256) void scores_kernel(
    const float* __restrict__ qt, const float* __restrict__ qb,
    const float* __restrict__ keys, float* __restrict__ wout)
{
    __shared__ float qt_s[HC][QPAD];
    __shared__ float k_s[HC][KPAD];
    const int t   = threadIdx.x;
    const int kt  = blockIdx.x;      // 0..63
    const int b   = blockIdx.y;      // 0..7
    const int k0g = kt * KT;

    const int tq = t >> 4;           // 0..15
    const int tk = t & 15;           // 0..15
    const int q0 = tq * 4, kk0 = tk * 8;

    float acc[4][8];
    #pragma unroll
    for (int i = 0; i < 4; ++i)
        #pragma unroll
        for (int j = 0; j < 8; ++j) acc[i][j] = 0.f;

    for (int hc = 0; hc < H; hc += HC) {
        __syncthreads();
        #pragma unroll
        for (int i = 0; i < 4; ++i) {
            int idx = t + 256 * i;
            int q = idx >> 4, hq = idx & 15;
            float4 v = *(const float4*)&qt[(b * TQ + q) * H + hc + hq * 4];
            qt_s[hq * 4 + 0][q] = v.x; qt_s[hq * 4 + 1][q] = v.y;
            qt_s[hq * 4 + 2][q] = v.z; qt_s[hq * 4 + 3][q] = v.w;
        }
        #pragma unroll
        for (int i = 0; i < 8; ++i) {
            int idx = t + 256 * i;
            int k = idx >> 4, hq = idx & 15;
            float4 v = *(const float4*)&keys[(size_t)(b * TK + k0g + k) * H + hc + hq * 4];
            k_s[hq * 4 + 0][k] = v.x; k_s[hq * 4 + 1][k] = v.y;
            k_s[hq * 4 + 2][k] = v.z; k_s[hq * 4 + 3][k] = v.w;
        }
        __syncthreads();
        #pragma unroll 8
        for (int h = 0; h < HC; ++h) {
            float4 qa  = *(const float4*)&qt_s[h][q0];
            float4 kb0 = *(const float4*)&k_s[h][kk0];
            float4 kb1 = *(const float4*)&k_s[h][kk0 + 4];
            const float qv[4] = {qa.x, qa.y, qa.z, qa.w};
            const float kv[8] = {kb0.x, kb0.y, kb0.z, kb0.w, kb1.x, kb1.y, kb1.z, kb1.w};
            #pragma unroll
            for (int i = 0; i < 4; ++i)
                #pragma unroll
                for (int j = 0; j < 8; ++j)
                    acc[i][j] += qv[i] * kv[j];
        }
    }
    #pragma unroll
    for (int i = 0; i < 4; ++i) {
        float bias = qb[b * TQ + q0 + i];
        float4 o0 = make_float4(acc[i][0] + bias, acc[i][1] + bias,
                                acc[i][2] + bias, acc[i][3] + bias);
        float4 o1 = make_float4(acc[i][4] + bias, acc[i][5] + bias,
                                acc[i][6] + bias, acc[i][7] + bias);
        float* dst = &wout[(size_t)(b * TQ + q0 + i) * TK + k0g + kk0];
        *(float4*)dst = o0;
        *(float4*)(dst + 4) = o1;
    }
}

// ---------------- Kernel 3: row softmax in place ---------------------------
__global__ __launch_bounds__(256) void softmax_kernel(float* __restrict__ w)
{
    const int r = blockIdx.x;     // 0..511
    const int t = threadIdx.x;
    float* row = w + (size_t)r * TK;
    __shared__ float redm[4];
    __shared__ float reds[4];

    float e[32];
    float m = -1e30f;
    #pragma unroll
    for (int i = 0; i < 32; ++i) { e[i] = row[t + i * 256]; m = fmaxf(m, e[i]); }
    for (int off = 32; off > 0; off >>= 1) m = fmaxf(m, __shfl_xor(m, off, 64));
    if ((t & 63) == 0) redm[t >> 6] = m;
    __syncthreads();
    m = fmaxf(fmaxf(redm[0], redm[1]), fmaxf(redm[2], redm[3]));

    float s = 0.f;
    #pragma unroll
    for (int i = 0; i < 32; ++i) { e[i] = __expf(e[i] - m); s += e[i]; }
    for (int off = 32; off > 0; off >>= 1) s += __shfl_xor(s, off, 64);
    if ((t & 63) == 0) reds[t >> 6] = s;
    __syncthreads();
    s = (reds[0] + reds[1]) + (reds[2] + reds[3]);
    const float inv = 1.0f / s;
    #pragma unroll
    for (int i = 0; i < 32; ++i) row[t + i * 256] = e[i] * inv;
}

// ---------------- Kernel 4a: context partials (split-k, no atomics) --------
// grid (KSPLIT, H/CH, B); block 256. Tile 64q x 64h over KPB=256 k's.
__global__ __launch_bounds__(256) void context_main_kernel(
    const float* __restrict__ w, const float* __restrict__ keys,
    float* __restrict__ part)
{
    __shared__ float w_s[TQ][CPAD];    // [q][k] natural layout, 64x68
    __shared__ float k_s[CKC][CPAD];   // [k][h]
    const int t  = threadIdx.x;
    const int ks = blockIdx.x;         // 0..KSPLIT-1
    const int ht = blockIdx.y;         // 0..3
    const int b  = blockIdx.z;         // 0..7
    const int tq = t >> 4, th = t & 15;
    const int q0 = tq * 4, h0 = th * 4;

    float acc[4][4];
    #pragma unroll
    for (int i = 0; i < 4; ++i)
        #pragma unroll
        for (int j = 0; j < 4; ++j) acc[i][j] = 0.f;

    for (int kc = 0; kc < KPB; kc += CKC) {
        const int k0 = ks * KPB + kc;
        __syncthreads();
        // stage w tile: w[b, q, k0+k] -> w_s[q][k]  (direct float4, conflict-free)
        #pragma unroll
        for (int i = 0; i < 4; ++i) {
            int idx = t + 256 * i;          // float4 slots in 64x64
            int q = idx >> 4, kf = idx & 15;
            *(float4*)&w_s[q][kf * 4] =
                *(const float4*)&w[(size_t)(b * TQ + q) * TK + k0 + kf * 4];
        }
        // stage keys tile: keys[b, k0+k, ht*CH+h] -> k_s[k][h]
        #pragma unroll
        for (int i = 0; i < 4; ++i) {
            int idx = t + 256 * i;
            int k = idx >> 4, hf = idx & 15;
            *(float4*)&k_s[k][hf * 4] =
                *(const float4*)&keys[(size_t)(b * TK + k0 + k) * H + ht * CH + hf * 4];
        }
        __syncthreads();
        #pragma unroll 4
        for (int k = 0; k < CKC; k += 4) {
            float4 wv[4], kv[4];
            #pragma unroll
            for (int i = 0; i < 4; ++i) wv[i] = *(const float4*)&w_s[q0 + i][k];
            #pragma unroll
            for (int j = 0; j < 4; ++j) kv[j] = *(const float4*)&k_s[k + j][h0];
            #pragma unroll
            for (int i = 0; i < 4; ++i) {
                acc[i][0] += wv[i].x * kv[0].x + wv[i].y * kv[1].x + wv[i].z * kv[2].x + wv[i].w * kv[3].x;
                acc[i][1] += wv[i].x * kv[0].y + wv[i].y * kv[1].y + wv[i].z * kv[2].y + wv[i].w * kv[3].y;
                acc[i][2] += wv[i].x * kv[0].z + wv[i].y * kv[1].z + wv[i].z * kv[2].z + wv[i].w * kv[3].z;
                acc[i][3] += wv[i].x * kv[0].w + wv[i].y * kv[1].w + wv[i].z * kv[2].w + wv[i].w * kv[3].w;
            }
        }
    }
    float* dst = part + (size_t)ks * (B * TQ * H);
    #pragma unroll
    for (int i = 0; i < 4; ++i) {
        float4 o = make_float4(acc[i][0], acc[i][1], acc[i][2], acc[i][3]);
        *(float4*)&dst[(size_t)(b * TQ + q0 + i) * H + ht * CH + h0] = o;
    }
}

// ---------------- Kernel 4b: reduce partials -> ctx ------------------------
__global__ __launch_bounds__(256) void context_reduce_kernel(
    const float* __restrict__ part, float* __restrict__ ctx)
{
    const int idx = blockIdx.x * 256 + threadIdx.x;   // float4 index, 32768 total
    float4 s = make_float4(0.f, 0.f, 0.f, 0.f);
    #pragma unroll 8
    for (int ks = 0; ks < KSPLIT; ++ks) {
        float4 v = *(const float4*)&part[(size_t)ks * (B * TQ * H) + (size_t)idx * 4];
        s.x += v.x; s.y += v.y; s.z += v.z; s.w += v.w;
    }
    *(float4*)&ctx[(size_t)idx * 4] = s;
}

// ---------------- Kernel 4 (fallback): atomic context ----------------------
__global__ __launch_bounds__(256) void context_kernel(
    const float* __restrict__ w, const float* __restrict__ keys,
    float* __restrict__ ctx)
{
    __shared__ float w_s[TQ][128];
    const int t  = threadIdx.x;
    const int kc = blockIdx.x;
    const int b  = blockIdx.y;
    const int hg = t & 63;
    const int qg = t >> 6;

    float acc[16][4];
    #pragma unroll
    for (int j = 0; j < 16; ++j)
        #pragma unroll
        for (int c = 0; c < 4; ++c) acc[j][c] = 0.f;

    for (int sub = 0; sub < 2; ++sub) {
        const int k0 = kc * KC + sub * 128;
        __syncthreads();
        #pragma unroll
        for (int i = 0; i < 8; ++i) {
            int idx = t + 256 * i;
            int q = idx >> 5, k4 = idx & 31;
            *(float4*)&w_s[q][k4 * 4] =
                *(const float4*)&w[(size_t)(b * TQ + q) * TK + k0 + k4 * 4];
        }
        __syncthreads();
        for (int k = 0; k < 128; k += 4) {
            float4 kv[4];
            #pragma unroll
            for (int u = 0; u < 4; ++u)
                kv[u] = *(const float4*)&keys[(size_t)(b * TK + k0 + k + u) * H + hg * 4];
            #pragma unroll
            for (int j = 0; j < 16; ++j) {
                float4 wv = *(const float4*)&w_s[qg * 16 + j][k];
                acc[j][0] += wv.x * kv[0].x + wv.y * kv[1].x + wv.z * kv[2].x + wv.w * kv[3].x;
                acc[j][1] += wv.x * kv[0].y + wv.y * kv[1].y + wv.z * kv[2].y + wv.w * kv[3].y;
                acc[j][2] += wv.x * kv[0].z + wv.y * kv[1].z + wv.z * kv[2].z + wv.w * kv[3].z;
                acc[j][3] += wv.x * kv[0].w + wv.y * kv[1].w + wv.z * kv[2].w + wv.w * kv[3].w;
            }
        }
    }
    #pragma unroll
    for (int j = 0; j < 16; ++j) {
        float* dst = &ctx[(size_t)(b * TQ + qg * 16 + j) * H + hg * 4];
        atomicAdd(dst + 0, acc[j][0]);
        atomicAdd(dst + 1, acc[j][1]);
        atomicAdd(dst + 2, acc[j][2]);
        atomicAdd(dst + 3, acc[j][3]);
    }
}

extern "C" void kernel_launch(void* const* d_in, const int* in_sizes, int n_in,
                              void* d_out, int out_size, void* d_ws, size_t ws_size,
                              hipStream_t stream) {
    const float* query = (const float*)d_in[0];
    const float* keys  = (const float*)d_in[1];
    const float* Wa_w  = (const float*)d_in[2];
    const float* Wa_b  = (const float*)d_in[3];

    float* ctx = (float*)d_out;                 // [B,TQ,H]
    float* wts = (float*)d_out + B * TQ * H;    // [B,TQ,TK]
    float* qt  = (float*)d_ws;                  // [B*TQ, H]
    float* qb  = qt + B * TQ * H;               // [B*TQ]
    float* part = qb + 512;                     // [KSPLIT][B*TQ*H]

    const size_t ws_needed = ((size_t)B * TQ * H + 512 +
                              (size_t)KSPLIT * B * TQ * H) * sizeof(float);

    qtransform_kernel<<<B * TQ, 256, 0, stream>>>(query, Wa_w, Wa_b, qt, qb);
    scores_kernel<<<dim3(TK / KT, B), 256, 0, stream>>>(qt, qb, keys, wts);
    softmax_kernel<<<B * TQ, 256, 0, stream>>>(wts);

    if (ws_size >= ws_needed) {
        context_main_kernel<<<dim3(KSPLIT, H / CH, B), 256, 0, stream>>>(wts, keys, part);
        context_reduce_kernel<<<(B * TQ * H / 4) / 256, 256, 0, stream>>>(part, ctx);
    } else {
        hipMemsetAsync(ctx, 0, (size_t)B * TQ * H * sizeof(float), stream);
        context_kernel<<<dim3(TK / KC, B), 256, 0, stream>>>(wts, keys, ctx);
    }
}

// Round 3
// 185.833 us; speedup vs baseline: 1.6566x; 1.0255x over previous
//
#include <hip/hip_runtime.h>

#define B 8
#define TQ 64
#define TK 8192
#define H 256

// scores v2 params
#define SKT 64      // k-tile per scores block
#define SHC 64      // h chunk staged in LDS
#define SPAD 68     // 64 + 4 -> row stride 272B = 68 words = 4 mod 32 banks

// context split-k params
#define KSPLIT 32
#define KPB (TK / KSPLIT)   // 256 k per block
#define CH 64               // h per block
#define CKC 64              // k chunk staged in LDS
#define CPAD 68

// ---------------- Kernel 1: qt = query @ Wa_w ; qb = query . Wa_b ----------
__global__ __launch_bounds__(256) void qtransform_kernel(
    const float* __restrict__ query, const float* __restrict__ Wa_w,
    const float* __restrict__ Wa_b, float* __restrict__ qt, float* __restrict__ qb)
{
    __shared__ float q_s[H];
    __shared__ float red[4];
    const int r = blockIdx.x;          // row in [0, B*TQ)
    const int t = threadIdx.x;         // 0..255
    q_s[t] = query[r * H + t];
    __syncthreads();

    float a0 = 0.f, a1 = 0.f, a2 = 0.f, a3 = 0.f;
    for (int o = 0; o < H; o += 4) {
        a0 += q_s[o + 0] * Wa_w[(o + 0) * H + t];
        a1 += q_s[o + 1] * Wa_w[(o + 1) * H + t];
        a2 += q_s[o + 2] * Wa_w[(o + 2) * H + t];
        a3 += q_s[o + 3] * Wa_w[(o + 3) * H + t];
    }
    qt[r * H + t] = (a0 + a1) + (a2 + a3);

    float p = q_s[t] * Wa_b[t];
    for (int off = 32; off > 0; off >>= 1) p += __shfl_down(p, off, 64);
    if ((t & 63) == 0) red[t >> 6] = p;
    __syncthreads();
    if (t == 0) qb[r] = (red[0] + red[1]) + (red[2] + red[3]);
}

// ---------------- Kernel 2: raw scores = qt . keys^T + qb ------------------
// grid (TK/SKT=128, B); block 256 (4 waves). Tile 64q x 64k, 4q x 4k / thread.
// Natural [row][h] LDS layout both sides: conflict-free staging and reads.
__global__ __launch_bounds__(256) void scores_kernel(
    const float* __restrict__ qt, const float* __restrict__ qb,
    const float* __restrict__ keys, float* __restrict__ wout)
{
    __shared__ float q_s[TQ][SPAD];
    __shared__ float k_s[SKT][SPAD];
    const int t   = threadIdx.x;
    const int kt  = blockIdx.x;      // 0..127
    const int b   = blockIdx.y;      // 0..7
    const int k0g = kt * SKT;

    const int tq = t >> 4;           // 0..15
    const int tk = t & 15;           // 0..15
    const int q0 = tq * 4;           // thread's 4 q rows: q0..q0+3
    // thread's 4 k rows: tk + 16*j  (16-lane group reads stride-1 rows: 2-way)

    float acc[4][4];
    #pragma unroll
    for (int i = 0; i < 4; ++i)
        #pragma unroll
        for (int j = 0; j < 4; ++j) acc[i][j] = 0.f;

    for (int hc = 0; hc < H; hc += SHC) {
        __syncthreads();
        // stage qt chunk: 64q x 64h, natural layout, float4
        #pragma unroll
        for (int i = 0; i < 4; ++i) {
            int idx = t + 256 * i;          // 0..1023 float4 slots
            int q = idx >> 4, hf = idx & 15;
            *(float4*)&q_s[q][hf * 4] =
                *(const float4*)&qt[(b * TQ + q) * H + hc + hf * 4];
        }
        // stage keys chunk: 64k x 64h, natural layout, float4
        #pragma unroll
        for (int i = 0; i < 4; ++i) {
            int idx = t + 256 * i;
            int k = idx >> 4, hf = idx & 15;
            *(float4*)&k_s[k][hf * 4] =
                *(const float4*)&keys[(size_t)(b * TK + k0g + k) * H + hc + hf * 4];
        }
        __syncthreads();
        #pragma unroll 4
        for (int h = 0; h < SHC; h += 4) {
            float4 qv[4], kv[4];
            #pragma unroll
            for (int i = 0; i < 4; ++i) qv[i] = *(const float4*)&q_s[q0 + i][h];
            #pragma unroll
            for (int j = 0; j < 4; ++j) kv[j] = *(const float4*)&k_s[tk + 16 * j][h];
            #pragma unroll
            for (int i = 0; i < 4; ++i)
                #pragma unroll
                for (int j = 0; j < 4; ++j)
                    acc[i][j] += qv[i].x * kv[j].x + qv[i].y * kv[j].y
                               + qv[i].z * kv[j].z + qv[i].w * kv[j].w;
        }
    }
    #pragma unroll
    for (int i = 0; i < 4; ++i) {
        const float bias = qb[b * TQ + q0 + i];
        float* dst = &wout[(size_t)(b * TQ + q0 + i) * TK + k0g + tk];
        #pragma unroll
        for (int j = 0; j < 4; ++j) dst[16 * j] = acc[i][j] + bias;
    }
}

// ---------------- Kernel 3: row softmax in place (1024 thr, 16 waves) ------
__global__ __launch_bounds__(1024) void softmax_kernel(float* __restrict__ w)
{
    const int r = blockIdx.x;     // 0..511
    const int t = threadIdx.x;    // 0..1023
    float4* row4 = (float4*)(w + (size_t)r * TK);
    __shared__ float redm[16];
    __shared__ float reds[16];
    const int wid = t >> 6, lane = t & 63;

    float4 v0 = row4[t];
    float4 v1 = row4[t + 1024];
    float m = fmaxf(fmaxf(fmaxf(v0.x, v0.y), fmaxf(v0.z, v0.w)),
                    fmaxf(fmaxf(v1.x, v1.y), fmaxf(v1.z, v1.w)));
    for (int off = 32; off > 0; off >>= 1) m = fmaxf(m, __shfl_xor(m, off, 64));
    if (lane == 0) redm[wid] = m;
    __syncthreads();
    m = redm[0];
    #pragma unroll
    for (int i = 1; i < 16; ++i) m = fmaxf(m, redm[i]);

    v0.x = __expf(v0.x - m); v0.y = __expf(v0.y - m);
    v0.z = __expf(v0.z - m); v0.w = __expf(v0.w - m);
    v1.x = __expf(v1.x - m); v1.y = __expf(v1.y - m);
    v1.z = __expf(v1.z - m); v1.w = __expf(v1.w - m);
    float s = (v0.x + v0.y + v0.z + v0.w) + (v1.x + v1.y + v1.z + v1.w);
    for (int off = 32; off > 0; off >>= 1) s += __shfl_xor(s, off, 64);
    if (lane == 0) reds[wid] = s;
    __syncthreads();
    s = reds[0];
    #pragma unroll
    for (int i = 1; i < 16; ++i) s += reds[i];
    const float inv = 1.0f / s;

    v0.x *= inv; v0.y *= inv; v0.z *= inv; v0.w *= inv;
    v1.x *= inv; v1.y *= inv; v1.z *= inv; v1.w *= inv;
    row4[t] = v0;
    row4[t + 1024] = v1;
}

// ---------------- Kernel 4a: context partials (split-k, no atomics) --------
// grid (KSPLIT, H/CH, B); block 256. Tile 64q x 64h over KPB=256 k's.
__global__ __launch_bounds__(256) void context_main_kernel(
    const float* __restrict__ w, const float* __restrict__ keys,
    float* __restrict__ part)
{
    __shared__ float w_s[TQ][CPAD];    // [q][k]
    __shared__ float k_s[CKC][CPAD];   // [k][h]
    const int t  = threadIdx.x;
    const int ks = blockIdx.x;         // 0..KSPLIT-1
    const int ht = blockIdx.y;         // 0..3
    const int b  = blockIdx.z;         // 0..7
    const int tq = t >> 4, th = t & 15;
    const int q0 = tq * 4, h0 = th * 4;

    float acc[4][4];
    #pragma unroll
    for (int i = 0; i < 4; ++i)
        #pragma unroll
        for (int j = 0; j < 4; ++j) acc[i][j] = 0.f;

    for (int kc = 0; kc < KPB; kc += CKC) {
        const int k0 = ks * KPB + kc;
        __syncthreads();
        #pragma unroll
        for (int i = 0; i < 4; ++i) {
            int idx = t + 256 * i;
            int q = idx >> 4, kf = idx & 15;
            *(float4*)&w_s[q][kf * 4] =
                *(const float4*)&w[(size_t)(b * TQ + q) * TK + k0 + kf * 4];
        }
        #pragma unroll
        for (int i = 0; i < 4; ++i) {
            int idx = t + 256 * i;
            int k = idx >> 4, hf = idx & 15;
            *(float4*)&k_s[k][hf * 4] =
                *(const float4*)&keys[(size_t)(b * TK + k0 + k) * H + ht * CH + hf * 4];
        }
        __syncthreads();
        #pragma unroll 4
        for (int k = 0; k < CKC; k += 4) {
            float4 wv[4], kv[4];
            #pragma unroll
            for (int i = 0; i < 4; ++i) wv[i] = *(const float4*)&w_s[q0 + i][k];
            #pragma unroll
            for (int j = 0; j < 4; ++j) kv[j] = *(const float4*)&k_s[k + j][h0];
            #pragma unroll
            for (int i = 0; i < 4; ++i) {
                acc[i][0] += wv[i].x * kv[0].x + wv[i].y * kv[1].x + wv[i].z * kv[2].x + wv[i].w * kv[3].x;
                acc[i][1] += wv[i].x * kv[0].y + wv[i].y * kv[1].y + wv[i].z * kv[2].y + wv[i].w * kv[3].y;
                acc[i][2] += wv[i].x * kv[0].z + wv[i].y * kv[1].z + wv[i].z * kv[2].z + wv[i].w * kv[3].z;
                acc[i][3] += wv[i].x * kv[0].w + wv[i].y * kv[1].w + wv[i].z * kv[2].w + wv[i].w * kv[3].w;
            }
        }
    }
    float* dst = part + (size_t)ks * (B * TQ * H);
    #pragma unroll
    for (int i = 0; i < 4; ++i) {
        float4 o = make_float4(acc[i][0], acc[i][1], acc[i][2], acc[i][3]);
        *(float4*)&dst[(size_t)(b * TQ + q0 + i) * H + ht * CH + h0] = o;
    }
}

// ---------------- Kernel 4b: reduce partials -> ctx ------------------------
__global__ __launch_bounds__(256) void context_reduce_kernel(
    const float* __restrict__ part, float* __restrict__ ctx)
{
    const int idx = blockIdx.x * 256 + threadIdx.x;   // float4 index, 32768 total
    float4 s = make_float4(0.f, 0.f, 0.f, 0.f);
    #pragma unroll 8
    for (int ks = 0; ks < KSPLIT; ++ks) {
        float4 v = *(const float4*)&part[(size_t)ks * (B * TQ * H) + (size_t)idx * 4];
        s.x += v.x; s.y += v.y; s.z += v.z; s.w += v.w;
    }
    *(float4*)&ctx[(size_t)idx * 4] = s;
}

extern "C" void kernel_launch(void* const* d_in, const int* in_sizes, int n_in,
                              void* d_out, int out_size, void* d_ws, size_t ws_size,
                              hipStream_t stream) {
    const float* query = (const float*)d_in[0];
    const float* keys  = (const float*)d_in[1];
    const float* Wa_w  = (const float*)d_in[2];
    const float* Wa_b  = (const float*)d_in[3];

    float* ctx = (float*)d_out;                 // [B,TQ,H]
    float* wts = (float*)d_out + B * TQ * H;    // [B,TQ,TK]
    float* qt  = (float*)d_ws;                  // [B*TQ, H]
    float* qb  = qt + B * TQ * H;               // [B*TQ]
    float* part = qb + 512;                     // [KSPLIT][B*TQ*H]

    qtransform_kernel<<<B * TQ, 256, 0, stream>>>(query, Wa_w, Wa_b, qt, qb);
    scores_kernel<<<dim3(TK / SKT, B), 256, 0, stream>>>(qt, qb, keys, wts);
    softmax_kernel<<<B * TQ, 1024, 0, stream>>>(wts);
    context_main_kernel<<<dim3(KSPLIT, H / CH, B), 256, 0, stream>>>(wts, keys, part);
    context_reduce_kernel<<<(B * TQ * H / 4) / 256, 256, 0, stream>>>(part, ctx);
}

// Round 4
// 175.225 us; speedup vs baseline: 1.7569x; 1.0605x over previous
//
#include <hip/hip_runtime.h>

#define B 8
#define TQ 64
#define TK 8192
#define H 256

// scores mfma params
#define SPADB 72    // 64 bf16 + 8 pad -> row stride 144B (2-way bank alias = free)

// context split-k params
#define KSPLIT 32
#define KPB (TK / KSPLIT)   // 256 k per block
#define CH 64               // h per block
#define CKC 64              // k chunk staged in LDS
#define CPAD 68

typedef __attribute__((ext_vector_type(8))) short bf16x8;
typedef __attribute__((ext_vector_type(4))) float f32x4;
typedef __attribute__((ext_vector_type(4))) unsigned short u16x4;

static __device__ inline unsigned short f2bf(float x) {
    unsigned int u = __float_as_uint(x);
    unsigned int r = (u + 0x7fffu + ((u >> 16) & 1u)) >> 16;   // RNE
    return (unsigned short)r;
}
static __device__ inline float bf2f(unsigned short h) {
    return __uint_as_float(((unsigned int)h) << 16);
}

// ---------------- Kernel 1: qt = query @ Wa_w ; qb = query . Wa_b ----------
__global__ __launch_bounds__(256) void qtransform_kernel(
    const float* __restrict__ query, const float* __restrict__ Wa_w,
    const float* __restrict__ Wa_b, float* __restrict__ qt, float* __restrict__ qb)
{
    __shared__ float q_s[H];
    __shared__ float red[4];
    const int r = blockIdx.x;          // row in [0, B*TQ)
    const int t = threadIdx.x;         // 0..255
    q_s[t] = query[r * H + t];
    __syncthreads();

    float a0 = 0.f, a1 = 0.f, a2 = 0.f, a3 = 0.f;
    for (int o = 0; o < H; o += 4) {
        a0 += q_s[o + 0] * Wa_w[(o + 0) * H + t];
        a1 += q_s[o + 1] * Wa_w[(o + 1) * H + t];
        a2 += q_s[o + 2] * Wa_w[(o + 2) * H + t];
        a3 += q_s[o + 3] * Wa_w[(o + 3) * H + t];
    }
    qt[r * H + t] = (a0 + a1) + (a2 + a3);

    float p = q_s[t] * Wa_b[t];
    for (int off = 32; off > 0; off >>= 1) p += __shfl_down(p, off, 64);
    if ((t & 63) == 0) red[t >> 6] = p;
    __syncthreads();
    if (t == 0) qb[r] = (red[0] + red[1]) + (red[2] + red[3]);
}

// ---------------- Kernel 2: raw scores = qt . keys^T + qb  (bf16-split MFMA)
// grid (TK/64=128, B); block 256 (4 waves). Tile 64q x 64k, K-dim = H=256.
// fp32 -> hi/lo bf16 split fused into staging; 3 MFMAs (hh, hl, lh) per tile.
__global__ __launch_bounds__(256) void scores_kernel(
    const float* __restrict__ qt, const float* __restrict__ qb,
    const float* __restrict__ keys, float* __restrict__ wout)
{
    __shared__ unsigned short a_hi[TQ][SPADB], a_lo[TQ][SPADB];
    __shared__ unsigned short b_hi[64][SPADB], b_lo[64][SPADB];
    const int t    = threadIdx.x;
    const int kt   = blockIdx.x;     // 0..127
    const int b    = blockIdx.y;     // 0..7
    const int k0g  = kt * 64;
    const int w    = t >> 6;         // wave 0..3 -> q rows 16w..16w+15
    const int lane = t & 63;
    const int lrow = lane & 15;
    const int lgrp = lane >> 4;      // 0..3

    f32x4 acc[4];
    #pragma unroll
    for (int nt = 0; nt < 4; ++nt) acc[nt] = (f32x4){0.f, 0.f, 0.f, 0.f};

    for (int hc = 0; hc < H; hc += 64) {
        __syncthreads();
        // stage qt tile (64q x 64h) and keys tile (64k x 64h), split hi/lo
        #pragma unroll
        for (int i = 0; i < 4; ++i) {
            int idx = t + 256 * i;          // 1024 float4 slots per tile
            int row = idx >> 4, hf = idx & 15;
            float4 va = *(const float4*)&qt[(b * TQ + row) * H + hc + hf * 4];
            u16x4 h4, l4;
            h4[0] = f2bf(va.x); l4[0] = f2bf(va.x - bf2f(h4[0]));
            h4[1] = f2bf(va.y); l4[1] = f2bf(va.y - bf2f(h4[1]));
            h4[2] = f2bf(va.z); l4[2] = f2bf(va.z - bf2f(h4[2]));
            h4[3] = f2bf(va.w); l4[3] = f2bf(va.w - bf2f(h4[3]));
            *(u16x4*)&a_hi[row][hf * 4] = h4;
            *(u16x4*)&a_lo[row][hf * 4] = l4;

            float4 vb = *(const float4*)&keys[(size_t)(b * TK + k0g + row) * H + hc + hf * 4];
            u16x4 g4, m4;
            g4[0] = f2bf(vb.x); m4[0] = f2bf(vb.x - bf2f(g4[0]));
            g4[1] = f2bf(vb.y); m4[1] = f2bf(vb.y - bf2f(g4[1]));
            g4[2] = f2bf(vb.z); m4[2] = f2bf(vb.z - bf2f(g4[2]));
            g4[3] = f2bf(vb.w); m4[3] = f2bf(vb.w - bf2f(g4[3]));
            *(u16x4*)&b_hi[row][hf * 4] = g4;
            *(u16x4*)&b_lo[row][hf * 4] = m4;
        }
        __syncthreads();
        #pragma unroll
        for (int hs = 0; hs < 64; hs += 32) {
            bf16x8 ah = *(const bf16x8*)&a_hi[16 * w + lrow][hs + lgrp * 8];
            bf16x8 al = *(const bf16x8*)&a_lo[16 * w + lrow][hs + lgrp * 8];
            #pragma unroll
            for (int nt = 0; nt < 4; ++nt) {
                bf16x8 bh = *(const bf16x8*)&b_hi[16 * nt + lrow][hs + lgrp * 8];
                bf16x8 bl = *(const bf16x8*)&b_lo[16 * nt + lrow][hs + lgrp * 8];
                acc[nt] = __builtin_amdgcn_mfma_f32_16x16x32_bf16(ah, bh, acc[nt], 0, 0, 0);
                acc[nt] = __builtin_amdgcn_mfma_f32_16x16x32_bf16(ah, bl, acc[nt], 0, 0, 0);
                acc[nt] = __builtin_amdgcn_mfma_f32_16x16x32_bf16(al, bh, acc[nt], 0, 0, 0);
            }
        }
    }
    // epilogue: D[row][col] with col = lane&15, row = lgrp*4 + j (within 16x16)
    #pragma unroll
    for (int j = 0; j < 4; ++j) {
        const int qrow = 16 * w + lgrp * 4 + j;
        const float bias = qb[b * TQ + qrow];
        float* dst = &wout[(size_t)(b * TQ + qrow) * TK + k0g + lrow];
        #pragma unroll
        for (int nt = 0; nt < 4; ++nt) dst[16 * nt] = acc[nt][j] + bias;
    }
}

// ---------------- Kernel 3: row softmax in place (1024 thr, 16 waves) ------
__global__ __launch_bounds__(1024) void softmax_kernel(float* __restrict__ w)
{
    const int r = blockIdx.x;     // 0..511
    const int t = threadIdx.x;    // 0..1023
    float4* row4 = (float4*)(w + (size_t)r * TK);
    __shared__ float redm[16];
    __shared__ float reds[16];
    const int wid = t >> 6, lane = t & 63;

    float4 v0 = row4[t];
    float4 v1 = row4[t + 1024];
    float m = fmaxf(fmaxf(fmaxf(v0.x, v0.y), fmaxf(v0.z, v0.w)),
                    fmaxf(fmaxf(v1.x, v1.y), fmaxf(v1.z, v1.w)));
    for (int off = 32; off > 0; off >>= 1) m = fmaxf(m, __shfl_xor(m, off, 64));
    if (lane == 0) redm[wid] = m;
    __syncthreads();
    m = redm[0];
    #pragma unroll
    for (int i = 1; i < 16; ++i) m = fmaxf(m, redm[i]);

    v0.x = __expf(v0.x - m); v0.y = __expf(v0.y - m);
    v0.z = __expf(v0.z - m); v0.w = __expf(v0.w - m);
    v1.x = __expf(v1.x - m); v1.y = __expf(v1.y - m);
    v1.z = __expf(v1.z - m); v1.w = __expf(v1.w - m);
    float s = (v0.x + v0.y + v0.z + v0.w) + (v1.x + v1.y + v1.z + v1.w);
    for (int off = 32; off > 0; off >>= 1) s += __shfl_xor(s, off, 64);
    if (lane == 0) reds[wid] = s;
    __syncthreads();
    s = reds[0];
    #pragma unroll
    for (int i = 1; i < 16; ++i) s += reds[i];
    const float inv = 1.0f / s;

    v0.x *= inv; v0.y *= inv; v0.z *= inv; v0.w *= inv;
    v1.x *= inv; v1.y *= inv; v1.z *= inv; v1.w *= inv;
    row4[t] = v0;
    row4[t + 1024] = v1;
}

// ---------------- Kernel 4a: context partials (split-k, no atomics) --------
__global__ __launch_bounds__(256) void context_main_kernel(
    const float* __restrict__ w, const float* __restrict__ keys,
    float* __restrict__ part)
{
    __shared__ float w_s[TQ][CPAD];    // [q][k]
    __shared__ float k_s[CKC][CPAD];   // [k][h]
    const int t  = threadIdx.x;
    const int ks = blockIdx.x;         // 0..KSPLIT-1
    const int ht = blockIdx.y;         // 0..3
    const int b  = blockIdx.z;         // 0..7
    const int tq = t >> 4, th = t & 15;
    const int q0 = tq * 4, h0 = th * 4;

    float acc[4][4];
    #pragma unroll
    for (int i = 0; i < 4; ++i)
        #pragma unroll
        for (int j = 0; j < 4; ++j) acc[i][j] = 0.f;

    for (int kc = 0; kc < KPB; kc += CKC) {
        const int k0 = ks * KPB + kc;
        __syncthreads();
        #pragma unroll
        for (int i = 0; i < 4; ++i) {
            int idx = t + 256 * i;
            int q = idx >> 4, kf = idx & 15;
            *(float4*)&w_s[q][kf * 4] =
                *(const float4*)&w[(size_t)(b * TQ + q) * TK + k0 + kf * 4];
        }
        #pragma unroll
        for (int i = 0; i < 4; ++i) {
            int idx = t + 256 * i;
            int k = idx >> 4, hf = idx & 15;
            *(float4*)&k_s[k][hf * 4] =
                *(const float4*)&keys[(size_t)(b * TK + k0 + k) * H + ht * CH + hf * 4];
        }
        __syncthreads();
        #pragma unroll 4
        for (int k = 0; k < CKC; k += 4) {
            float4 wv[4], kv[4];
            #pragma unroll
            for (int i = 0; i < 4; ++i) wv[i] = *(const float4*)&w_s[q0 + i][k];
            #pragma unroll
            for (int j = 0; j < 4; ++j) kv[j] = *(const float4*)&k_s[k + j][h0];
            #pragma unroll
            for (int i = 0; i < 4; ++i) {
                acc[i][0] += wv[i].x * kv[0].x + wv[i].y * kv[1].x + wv[i].z * kv[2].x + wv[i].w * kv[3].x;
                acc[i][1] += wv[i].x * kv[0].y + wv[i].y * kv[1].y + wv[i].z * kv[2].y + wv[i].w * kv[3].y;
                acc[i][2] += wv[i].x * kv[0].z + wv[i].y * kv[1].z + wv[i].z * kv[2].z + wv[i].w * kv[3].z;
                acc[i][3] += wv[i].x * kv[0].w + wv[i].y * kv[1].w + wv[i].z * kv[2].w + wv[i].w * kv[3].w;
            }
        }
    }
    float* dst = part + (size_t)ks * (B * TQ * H);
    #pragma unroll
    for (int i = 0; i < 4; ++i) {
        float4 o = make_float4(acc[i][0], acc[i][1], acc[i][2], acc[i][3]);
        *(float4*)&dst[(size_t)(b * TQ + q0 + i) * H + ht * CH + h0] = o;
    }
}

// ---------------- Kernel 4b: reduce partials -> ctx ------------------------
__global__ __launch_bounds__(256) void context_reduce_kernel(
    const float* __restrict__ part, float* __restrict__ ctx)
{
    const int idx = blockIdx.x * 256 + threadIdx.x;   // float4 index, 32768 total
    float4 s = make_float4(0.f, 0.f, 0.f, 0.f);
    #pragma unroll 8
    for (int ks = 0; ks < KSPLIT; ++ks) {
        float4 v = *(const float4*)&part[(size_t)ks * (B * TQ * H) + (size_t)idx * 4];
        s.x += v.x; s.y += v.y; s.z += v.z; s.w += v.w;
    }
    *(float4*)&ctx[(size_t)idx * 4] = s;
}

extern "C" void kernel_launch(void* const* d_in, const int* in_sizes, int n_in,
                              void* d_out, int out_size, void* d_ws, size_t ws_size,
                              hipStream_t stream) {
    const float* query = (const float*)d_in[0];
    const float* keys  = (const float*)d_in[1];
    const float* Wa_w  = (const float*)d_in[2];
    const float* Wa_b  = (const float*)d_in[3];

    float* ctx = (float*)d_out;                 // [B,TQ,H]
    float* wts = (float*)d_out + B * TQ * H;    // [B,TQ,TK]
    float* qt  = (float*)d_ws;                  // [B*TQ, H]
    float* qb  = qt + B * TQ * H;               // [B*TQ]
    float* part = qb + 512;                     // [KSPLIT][B*TQ*H]

    qtransform_kernel<<<B * TQ, 256, 0, stream>>>(query, Wa_w, Wa_b, qt, qb);
    scores_kernel<<<dim3(TK / 64, B), 256, 0, stream>>>(qt, qb, keys, wts);
    softmax_kernel<<<B * TQ, 1024, 0, stream>>>(wts);
    context_main_kernel<<<dim3(KSPLIT, H / CH, B), 256, 0, stream>>>(wts, keys, part);
    context_reduce_kernel<<<(B * TQ * H / 4) / 256, 256, 0, stream>>>(part, ctx);
}

// Round 5
// 158.915 us; speedup vs baseline: 1.9372x; 1.1026x over previous
//
#include <hip/hip_runtime.h>

#define B 8
#define TQ 64
#define TK 8192
#define H 256

// scores mfma params
#define SPADB 72    // 64 bf16 + 8 pad -> row stride 144B (16B-aligned, 2-way bank alias = free)

// context split-k params
#define KSPLIT 32
#define KPB (TK / KSPLIT)   // 256 k per block
#define CRS 72              // context LDS keysT row stride (ushorts)

typedef __attribute__((ext_vector_type(8))) short bf16x8;
typedef __attribute__((ext_vector_type(4))) float f32x4;
typedef __attribute__((ext_vector_type(4))) unsigned short u16x4;
typedef __attribute__((ext_vector_type(2))) unsigned int u32x2;

static __device__ inline unsigned short f2bf_rne(float x) {
    unsigned int u = __float_as_uint(x);
    unsigned int r = (u + 0x7fffu + ((u >> 16) & 1u)) >> 16;   // RNE
    return (unsigned short)r;
}

// ---------------- Kernel 1: qt-split = (query @ Wa_w) hi/lo ; qb -----------
__global__ __launch_bounds__(256) void qtransform_kernel(
    const float* __restrict__ query, const float* __restrict__ Wa_w,
    const float* __restrict__ Wa_b, unsigned short* __restrict__ qthi,
    unsigned short* __restrict__ qtlo, float* __restrict__ qb)
{
    __shared__ float q_s[H];
    __shared__ float red[4];
    const int r = blockIdx.x;          // row in [0, B*TQ)
    const int t = threadIdx.x;         // 0..255
    q_s[t] = query[r * H + t];
    __syncthreads();

    float a0 = 0.f, a1 = 0.f, a2 = 0.f, a3 = 0.f;
    for (int o = 0; o < H; o += 4) {
        a0 += q_s[o + 0] * Wa_w[(o + 0) * H + t];
        a1 += q_s[o + 1] * Wa_w[(o + 1) * H + t];
        a2 += q_s[o + 2] * Wa_w[(o + 2) * H + t];
        a3 += q_s[o + 3] * Wa_w[(o + 3) * H + t];
    }
    const float s = (a0 + a1) + (a2 + a3);
    const unsigned int u = __float_as_uint(s);
    const float hif = __uint_as_float(u & 0xFFFF0000u);
    const float lof = s - hif;                     // exact
    qthi[r * H + t] = (unsigned short)(u >> 16);
    qtlo[r * H + t] = (unsigned short)(__float_as_uint(lof) >> 16);

    float p = q_s[t] * Wa_b[t];
    for (int off = 32; off > 0; off >>= 1) p += __shfl_down(p, off, 64);
    if ((t & 63) == 0) red[t >> 6] = p;
    __syncthreads();
    if (t == 0) qb[r] = (red[0] + red[1]) + (red[2] + red[3]);
}

// ---------------- Kernel 2: raw scores = qt . keys^T + qb  (bf16-split MFMA)
// grid (TK/64=128, B); block 256 (4 waves). Tile 64q x 64k, K-dim = H=256.
// Trunc split of keys fused into staging; khi side-written for context MFMA.
__global__ __launch_bounds__(256) void scores_kernel(
    const unsigned short* __restrict__ qthi, const unsigned short* __restrict__ qtlo,
    const float* __restrict__ qb, const float* __restrict__ keys,
    unsigned short* __restrict__ khi_ws, float* __restrict__ wout)
{
    __shared__ unsigned short a_hi[TQ][SPADB], a_lo[TQ][SPADB];
    __shared__ unsigned short b_hi[64][SPADB], b_lo[64][SPADB];
    const int t    = threadIdx.x;
    const int kt   = blockIdx.x;     // 0..127
    const int b    = blockIdx.y;     // 0..7
    const int k0g  = kt * 64;
    const int w    = t >> 6;         // wave 0..3 -> q rows 16w..16w+15
    const int lane = t & 63;
    const int lrow = lane & 15;
    const int lgrp = lane >> 4;      // 0..3

    f32x4 acc[4];
    #pragma unroll
    for (int nt = 0; nt < 4; ++nt) acc[nt] = (f32x4){0.f, 0.f, 0.f, 0.f};

    for (int hc = 0; hc < H; hc += 64) {
        __syncthreads();
        // stage pre-split qt tiles (pure copy, no VALU)
        #pragma unroll
        for (int i = 0; i < 4; ++i) {
            int idx = t + 256 * i;          // 1024 u16x4 slots
            int row = idx >> 4, hf = idx & 15;
            *(u16x4*)&a_hi[row][hf * 4] =
                *(const u16x4*)&qthi[(b * TQ + row) * H + hc + hf * 4];
            *(u16x4*)&a_lo[row][hf * 4] =
                *(const u16x4*)&qtlo[(b * TQ + row) * H + hc + hf * 4];
        }
        // stage keys tile with cheap truncation split; side-write khi
        #pragma unroll
        for (int i = 0; i < 4; ++i) {
            int idx = t + 256 * i;
            int row = idx >> 4, hf = idx & 15;
            float4 vb = *(const float4*)&keys[(size_t)(b * TK + k0g + row) * H + hc + hf * 4];
            unsigned int u0 = __float_as_uint(vb.x), u1 = __float_as_uint(vb.y);
            unsigned int u2 = __float_as_uint(vb.z), u3 = __float_as_uint(vb.w);
            unsigned int h01 = (u0 >> 16) | (u1 & 0xFFFF0000u);
            unsigned int h23 = (u2 >> 16) | (u3 & 0xFFFF0000u);
            float l0 = vb.x - __uint_as_float(u0 & 0xFFFF0000u);
            float l1 = vb.y - __uint_as_float(u1 & 0xFFFF0000u);
            float l2 = vb.z - __uint_as_float(u2 & 0xFFFF0000u);
            float l3 = vb.w - __uint_as_float(u3 & 0xFFFF0000u);
            unsigned int l01 = (__float_as_uint(l0) >> 16) | (__float_as_uint(l1) & 0xFFFF0000u);
            unsigned int l23 = (__float_as_uint(l2) >> 16) | (__float_as_uint(l3) & 0xFFFF0000u);
            *(u32x2*)&b_hi[row][hf * 4] = (u32x2){h01, h23};
            *(u32x2*)&b_lo[row][hf * 4] = (u32x2){l01, l23};
            *(u32x2*)&khi_ws[((size_t)b * TK + k0g + row) * H + hc + hf * 4] = (u32x2){h01, h23};
        }
        __syncthreads();
        #pragma unroll
        for (int hs = 0; hs < 64; hs += 32) {
            bf16x8 ah = *(const bf16x8*)&a_hi[16 * w + lrow][hs + lgrp * 8];
            bf16x8 al = *(const bf16x8*)&a_lo[16 * w + lrow][hs + lgrp * 8];
            #pragma unroll
            for (int nt = 0; nt < 4; ++nt) {
                bf16x8 bh = *(const bf16x8*)&b_hi[16 * nt + lrow][hs + lgrp * 8];
                bf16x8 bl = *(const bf16x8*)&b_lo[16 * nt + lrow][hs + lgrp * 8];
                acc[nt] = __builtin_amdgcn_mfma_f32_16x16x32_bf16(ah, bh, acc[nt], 0, 0, 0);
                acc[nt] = __builtin_amdgcn_mfma_f32_16x16x32_bf16(ah, bl, acc[nt], 0, 0, 0);
                acc[nt] = __builtin_amdgcn_mfma_f32_16x16x32_bf16(al, bh, acc[nt], 0, 0, 0);
            }
        }
    }
    // epilogue: D col = lane&15 (k), row = lgrp*4 + j (q)
    #pragma unroll
    for (int j = 0; j < 4; ++j) {
        const int qrow = 16 * w + lgrp * 4 + j;
        const float bias = qb[b * TQ + qrow];
        float* dst = &wout[(size_t)(b * TQ + qrow) * TK + k0g + lrow];
        #pragma unroll
        for (int nt = 0; nt < 4; ++nt) dst[16 * nt] = acc[nt][j] + bias;
    }
}

// ---------------- Kernel 3: row softmax in place + phi (bf16) side-output --
__global__ __launch_bounds__(1024) void softmax_kernel(
    float* __restrict__ w, unsigned short* __restrict__ phi)
{
    const int r = blockIdx.x;     // 0..511
    const int t = threadIdx.x;    // 0..1023
    float4* row4 = (float4*)(w + (size_t)r * TK);
    __shared__ float redm[16];
    __shared__ float reds[16];
    const int wid = t >> 6, lane = t & 63;

    float4 v0 = row4[t];
    float4 v1 = row4[t + 1024];
    float m = fmaxf(fmaxf(fmaxf(v0.x, v0.y), fmaxf(v0.z, v0.w)),
                    fmaxf(fmaxf(v1.x, v1.y), fmaxf(v1.z, v1.w)));
    for (int off = 32; off > 0; off >>= 1) m = fmaxf(m, __shfl_xor(m, off, 64));
    if (lane == 0) redm[wid] = m;
    __syncthreads();
    m = redm[0];
    #pragma unroll
    for (int i = 1; i < 16; ++i) m = fmaxf(m, redm[i]);

    v0.x = __expf(v0.x - m); v0.y = __expf(v0.y - m);
    v0.z = __expf(v0.z - m); v0.w = __expf(v0.w - m);
    v1.x = __expf(v1.x - m); v1.y = __expf(v1.y - m);
    v1.z = __expf(v1.z - m); v1.w = __expf(v1.w - m);
    float s = (v0.x + v0.y + v0.z + v0.w) + (v1.x + v1.y + v1.z + v1.w);
    for (int off = 32; off > 0; off >>= 1) s += __shfl_xor(s, off, 64);
    if (lane == 0) reds[wid] = s;
    __syncthreads();
    s = reds[0];
    #pragma unroll
    for (int i = 1; i < 16; ++i) s += reds[i];
    const float inv = 1.0f / s;

    v0.x *= inv; v0.y *= inv; v0.z *= inv; v0.w *= inv;
    v1.x *= inv; v1.y *= inv; v1.z *= inv; v1.w *= inv;
    row4[t] = v0;
    row4[t + 1024] = v1;

    unsigned short* prow = phi + (size_t)r * TK;
    u16x4 p0, p1;
    p0[0] = f2bf_rne(v0.x); p0[1] = f2bf_rne(v0.y);
    p0[2] = f2bf_rne(v0.z); p0[3] = f2bf_rne(v0.w);
    p1[0] = f2bf_rne(v1.x); p1[1] = f2bf_rne(v1.y);
    p1[2] = f2bf_rne(v1.z); p1[3] = f2bf_rne(v1.w);
    *(u16x4*)&prow[t * 4] = p0;
    *(u16x4*)&prow[4096 + t * 4] = p1;
}

// ---------------- Kernel 4a: context partials via MFMA (split-k) -----------
// grid (KSPLIT, 4, B); block 256 (4 waves). 64q x 64h tile over KPB=256 k.
// B-operand keys^T built in LDS via k-block XOR swizzle (conflict-free).
__global__ __launch_bounds__(256) void context_main_kernel(
    const unsigned short* __restrict__ phi, const unsigned short* __restrict__ khi,
    float* __restrict__ part)
{
    __shared__ unsigned short kT[64 * CRS];   // [h][k] transposed, swizzled
    const int t    = threadIdx.x;
    const int ks   = blockIdx.x;     // 0..KSPLIT-1
    const int ht   = blockIdx.y;     // 0..3
    const int b    = blockIdx.z;     // 0..7
    const int w    = t >> 6;         // wave -> q rows 16w..16w+15
    const int lane = t & 63;
    const int lrow = lane & 15;
    const int lgrp = lane >> 4;

    f32x4 acc[4];
    #pragma unroll
    for (int nt = 0; nt < 4; ++nt) acc[nt] = (f32x4){0.f, 0.f, 0.f, 0.f};

    const int kbase = ks * KPB;
    for (int c = 0; c < KPB; c += 64) {
        __syncthreads();
        // stage khi tile [64k][64h] -> kT[h][k] with kblk ^= (h>>3)&7 swizzle
        #pragma unroll
        for (int i = 0; i < 4; ++i) {
            int idx = t + 256 * i;
            int k = idx >> 4, hq = idx & 15;
            u16x4 v = *(const u16x4*)&khi[((size_t)b * TK + kbase + c + k) * H + ht * 64 + hq * 4];
            #pragma unroll
            for (int c4 = 0; c4 < 4; ++c4) {
                int h = hq * 4 + c4;
                kT[h * CRS + (((k >> 3) ^ ((h >> 3) & 7)) << 3) + (k & 7)] = v[c4];
            }
        }
        __syncthreads();
        #pragma unroll
        for (int kc = 0; kc < 64; kc += 32) {
            bf16x8 af = *(const bf16x8*)&phi[((size_t)(b * TQ) + 16 * w + lrow) * TK
                                             + kbase + c + kc + lgrp * 8];
            #pragma unroll
            for (int nt = 0; nt < 4; ++nt) {
                int h = 16 * nt + lrow;
                bf16x8 bf = *(const bf16x8*)&kT[h * CRS
                              + ((((kc >> 3) + lgrp) ^ ((h >> 3) & 7)) << 3)];
                acc[nt] = __builtin_amdgcn_mfma_f32_16x16x32_bf16(af, bf, acc[nt], 0, 0, 0);
            }
        }
    }
    // D: col = lane&15 (h), row = lgrp*4 + j (q)
    float* dst = part + (size_t)ks * (B * TQ * H);
    #pragma unroll
    for (int j = 0; j < 4; ++j) {
        const int qrow = 16 * w + lgrp * 4 + j;
        #pragma unroll
        for (int nt = 0; nt < 4; ++nt)
            dst[(size_t)(b * TQ + qrow) * H + ht * 64 + 16 * nt + lrow] = acc[nt][j];
    }
}

// ---------------- Kernel 4b: reduce partials -> ctx ------------------------
__global__ __launch_bounds__(256) void context_reduce_kernel(
    const float* __restrict__ part, float* __restrict__ ctx)
{
    const int idx = blockIdx.x * 256 + threadIdx.x;   // float4 index, 32768 total
    float4 s = make_float4(0.f, 0.f, 0.f, 0.f);
    #pragma unroll 8
    for (int ks = 0; ks < KSPLIT; ++ks) {
        float4 v = *(const float4*)&part[(size_t)ks * (B * TQ * H) + (size_t)idx * 4];
        s.x += v.x; s.y += v.y; s.z += v.z; s.w += v.w;
    }
    *(float4*)&ctx[(size_t)idx * 4] = s;
}

extern "C" void kernel_launch(void* const* d_in, const int* in_sizes, int n_in,
                              void* d_out, int out_size, void* d_ws, size_t ws_size,
                              hipStream_t stream) {
    const float* query = (const float*)d_in[0];
    const float* keys  = (const float*)d_in[1];
    const float* Wa_w  = (const float*)d_in[2];
    const float* Wa_b  = (const float*)d_in[3];

    float* ctx = (float*)d_out;                 // [B,TQ,H]
    float* wts = (float*)d_out + B * TQ * H;    // [B,TQ,TK]

    char* p = (char*)d_ws;
    float* part = (float*)p;            p += (size_t)KSPLIT * B * TQ * H * 4;  // 16.8MB
    unsigned short* khi = (unsigned short*)p;  p += (size_t)B * TK * H * 2;    // 33.5MB
    unsigned short* phi = (unsigned short*)p;  p += (size_t)B * TQ * TK * 2;   //  8.4MB
    unsigned short* qthi = (unsigned short*)p; p += (size_t)B * TQ * H * 2;
    unsigned short* qtlo = (unsigned short*)p; p += (size_t)B * TQ * H * 2;
    float* qb = (float*)p;

    qtransform_kernel<<<B * TQ, 256, 0, stream>>>(query, Wa_w, Wa_b, qthi, qtlo, qb);
    scores_kernel<<<dim3(TK / 64, B), 256, 0, stream>>>(qthi, qtlo, qb, keys, khi, wts);
    softmax_kernel<<<B * TQ, 1024, 0, stream>>>(wts, phi);
    context_main_kernel<<<dim3(KSPLIT, 4, B), 256, 0, stream>>>(phi, khi, part);
    context_reduce_kernel<<<(B * TQ * H / 4) / 256, 256, 0, stream>>>(part, ctx);
}